// Round 6
// baseline (148.755 us; speedup 1.0000x reference)
//
#include <hip/hip_runtime.h>

typedef _Float16 f16;
typedef _Float16 f16x2 __attribute__((ext_vector_type(2)));
typedef _Float16 f16x4 __attribute__((ext_vector_type(4)));
typedef _Float16 f16x8 __attribute__((ext_vector_type(8)));
typedef float    f32x4 __attribute__((ext_vector_type(4)));

#define NB   8
#define TE   2048
#define TD   2048
#define DIM  256
#define NBTD (NB * TD)
#define LOG2E 1.44269504088896340736f

#define AS1(p) ((const __attribute__((address_space(1))) void*)(p))
#define AS3(p) ((__attribute__((address_space(3))) void*)(p))
#define MFMA16(a,b,c) __builtin_amdgcn_mfma_f32_16x16x32_f16((a),(b),(c),0,0,0)
#define SHUF8(x,y) __builtin_shufflevector((x),(y),0,1,2,3,4,5,6,7)

__device__ __forceinline__ unsigned lds_u32(void* p) {
    return (unsigned)(size_t)((__attribute__((address_space(3))) void*)p);
}
// ds_read_b64_tr_b16 (validated r4/r5): per-lane 8B payload at its own addr; in-group
// permutation delivers out[l][j] = block[row j][col l&15] for a 4x16 row-major 128B
// block when per-lane addr = block_base + (l&15)*8.
__device__ __forceinline__ f16x4 tr_rd0(unsigned a) {
    f16x4 r;
    asm volatile("ds_read_b64_tr_b16 %0, %1" : "=v"(r) : "v"(a));
    return r;
}
__device__ __forceinline__ f16x4 tr_rd1(unsigned a) {   // +2048 = next e4 subtile row
    f16x4 r;
    asm volatile("ds_read_b64_tr_b16 %0, %1 offset:2048" : "=v"(r) : "v"(a));
    return r;
}

// ---------------- prep: enc fp32 -> f16, same layout ----------------
__global__ __launch_bounds__(256) void prep_kernel(const float* __restrict__ enc,
                                                   f16* __restrict__ ench) {
    size_t i = ((size_t)blockIdx.x * 256 + threadIdx.x) * 8;
    float4 v0 = *(const float4*)(enc + i);
    float4 v1 = *(const float4*)(enc + i + 4);
    f16x8 o;
    o[0]=(f16)v0.x; o[1]=(f16)v0.y; o[2]=(f16)v0.z; o[3]=(f16)v0.w;
    o[4]=(f16)v1.x; o[5]=(f16)v1.y; o[6]=(f16)v1.z; o[7]=(f16)v1.w;
    *(f16x8*)(ench + i) = o;
}

// ---------------- fused attention: 16-t waves, 16x16x32 MFMA, 3 waves/SIMD ----------------
// Registers were the round-5 occupancy cap (ctx 128 + qf 64 ~ 230 -> 2 waves/SIMD).
// 16-t waves halve both: qf 32, ctx 64 -> ~160 total -> 3 waves/SIMD (launch_bounds 256,3).
// Block = 4 waves x 16 t = 64 t; grid 32x8x3 = 768 = exactly 3 blocks/CU = 12 waves/CU.
// Per iter (e-tile 32): QK (2 e-frags x 8 ks) -> softmax (local 8-max + shfl16+shfl32,
// round-0 pattern) -> P to per-wave LDS (same-wave in-order DS) -> PV (16 dm-frags,
// A = enc^T via validated tr-reads). One __syncthreads/iter (NAT dbuf).
// NAT subtiled layout (proven): half(e,d) = ((e>>2)*16 + (d>>4))*64 + (e&3)*16 + (d&15)
// nsplit=3: split 0 -> ctxp f16; splits 1,2 -> out f32 (dec/ctx halves, free pre-combine).
// LDS 37,888 B -> 3 blocks/CU = 113.6 KB. ws need 17 MB << proven 33.8 MB bound.
__global__ __launch_bounds__(256, 3) void attn_kernel(
        const float* __restrict__ dec32,
        const f16*  __restrict__ enc_h,
        f16*   __restrict__ ctxp,
        f16x2* __restrict__ ml,
        float* __restrict__ out) {
    __shared__ __align__(16) char lds[37888];
    const int tid  = threadIdx.x;
    const int lane = tid & 63;
    const int wv   = tid >> 6;
    const int tcol = lane & 15;
    const int q    = lane >> 4;

    // XCD pinning: fid%8 = x&7 = b -> batch b resident on XCD b (enc 1MB + dec 2MB < 4MB L2)
    const int x  = blockIdx.x;            // 0..31
    const int b  = x & 7;
    const int xb = (x >> 3) | (blockIdx.y << 2);   // 0..31
    const int z  = blockIdx.z;            // 0..2
    const int t0 = xb * 64 + wv * 16;
    const int tile0 = (64 * z) / 3;       // 0,21,42
    const int iters = (64 * (z + 1)) / 3 - tile0;  // 21,21,22

    const char* encb = (const char*)(enc_h + (size_t)b * TE * DIM);

    // staging map (proven r2-r5): chunk c = i*256 + wv*64 + lane (16B), inverse subtile map
    const int c0  = wv * 64 + lane;
    const int e_l = ((c0 >> 7) << 2) | ((c0 >> 1) & 3);
    const int d_l = (((c0 >> 3) & 15) << 4) | ((c0 & 1) << 3);
    const int stage_goff = e_l * (DIM * 2) + d_l * 2;
    char* stage_dst = lds + wv * 1024;

    // QK A-read (16x16 A-frag: row e = mt*16+tcol, k-octet = ks*32 + q*8):
    //   byte = ((e>>2)+4mt)*2048 + (q>>1)*128 + (e&3)*32 + (q&1)*16 + ks*256
    const int qk_b0 = (tcol >> 2) * 2048 + (q >> 1) * 128 + (tcol & 3) * 32 + (q & 1) * 16;
    const int qk_b1 = qk_b0 + 8192;
    // PV tr-read: A-frag row d = dm*16 + tcol, e = q*8 + j:
    //   subtile (E=2q, D=dm) base + tcol*8  -> q*4096 + dm*128 + tcol*8 (pair via offset:2048)
    const unsigned tr_base = (unsigned)(q * 4096 + tcol * 8);
    const unsigned lds_base = lds_u32(lds);
    char* pb = lds + 32768 + wv * 1280;   // per-wave P: [t16][e32] f16, pitch 80

    // Q fragments: B[k = ks*32 + q*8 + j][n = t] ; 8 x f16x8 = 32 VGPR
    f16x8 qf[8];
    {
        const float* qrow = dec32 + ((size_t)b * TD + t0 + tcol) * DIM + q * 8;
        #pragma unroll
        for (int ks = 0; ks < 8; ks++) {
            float4 u = *(const float4*)(qrow + ks * 32);
            float4 v = *(const float4*)(qrow + ks * 32 + 4);
            f16x8 o;
            o[0]=(f16)u.x; o[1]=(f16)u.y; o[2]=(f16)u.z; o[3]=(f16)u.w;
            o[4]=(f16)v.x; o[5]=(f16)v.y; o[6]=(f16)v.z; o[7]=(f16)v.w;
            qf[ks] = o;
        }
    }

    { // stage tile0 -> buf0
        const char* s = encb + (size_t)tile0 * 16384 + stage_goff;
        #pragma unroll
        for (int i = 0; i < 4; i++)
            __builtin_amdgcn_global_load_lds(AS1(s + i * 4096), AS3(stage_dst + i * 4096), 16, 0, 0);
    }

    const f32x4 zero4 = {0.f, 0.f, 0.f, 0.f};
    float m_ = -INFINITY, l_ = 0.f;
    f32x4 ctx[16];
    #pragma unroll
    for (int dm = 0; dm < 16; dm++) ctx[dm] = zero4;

    __syncthreads();   // tile0 staged & drained

    for (int it = 0; it < iters; ++it) {
        const int nat = (it & 1) << 14;
        // stage next tile early: drained at THIS iter's end barrier
        if (it + 1 < iters) {
            const char* s = encb + (size_t)(tile0 + it + 1) * 16384 + stage_goff;
            char* dd = lds + (((it + 1) & 1) << 14) + wv * 1024;
            #pragma unroll
            for (int i = 0; i < 4; i++)
                __builtin_amdgcn_global_load_lds(AS1(s + i * 4096), AS3(dd + i * 4096), 16, 0, 0);
        }
        // ---- QK: St[e32][t16] = 2 e-frags x 8 k-steps ----
        f32x4 st0 = zero4, st1 = zero4;
        const char* natp = lds + nat;
        #pragma unroll
        for (int ks = 0; ks < 8; ks++) {
            f16x8 af0 = *(const f16x8*)(natp + qk_b0 + ks * 256);
            f16x8 af1 = *(const f16x8*)(natp + qk_b1 + ks * 256);
            st0 = MFMA16(af0, qf[ks], st0);
            st1 = MFMA16(af1, qf[ks], st1);
        }
        // ---- softmax (row t = tcol; e spread over q-groups + 2 frags) ----
        float mx = fmaxf(fmaxf(fmaxf(st0[0], st0[1]), fmaxf(st0[2], st0[3])),
                         fmaxf(fmaxf(st1[0], st1[1]), fmaxf(st1[2], st1[3])));
        mx = fmaxf(mx, __shfl_xor(mx, 16, 64));
        mx = fmaxf(mx, __shfl_xor(mx, 32, 64));
        float ms = (float)(f16)fmaxf(m_, mx);   // snap to f16 (>= m_, >= mx - ulp/2)
        float al = __builtin_amdgcn_exp2f((m_ - ms) * LOG2E);
        bool bump = ms > m_;
        m_ = ms;
        f16x4 pv0, pv1;
        float ssum = 0.f;
        #pragma unroll
        for (int r = 0; r < 4; r++) {           // e = q*4 + r  (frag0) / +16 (frag1)
            float p0 = __builtin_amdgcn_exp2f((st0[r] - ms) * LOG2E);
            float p1 = __builtin_amdgcn_exp2f((st1[r] - ms) * LOG2E);
            pv0[r] = (f16)p0; pv1[r] = (f16)p1;
            ssum += (float)pv0[r] + (float)pv1[r];
        }
        *(f16x4*)(pb + tcol * 80 + q * 8)      = pv0;
        *(f16x4*)(pb + tcol * 80 + 32 + q * 8) = pv1;
        ssum += __shfl_xor(ssum, 16, 64);
        ssum += __shfl_xor(ssum, 32, 64);
        l_ = l_ * al + ssum;
        if (__any(bump)) {
            #pragma unroll
            for (int dm = 0; dm < 16; dm++) {
                ctx[dm][0] *= al; ctx[dm][1] *= al;
                ctx[dm][2] *= al; ctx[dm][3] *= al;
            }
        }
        // ---- PV: ctx[d = dm*16 + row][t16]; A = enc^T tr-reads, B = P (same-wave LDS) ----
        f16x8 pf = *(const f16x8*)(pb + tcol * 80 + q * 16);   // P[t=tcol][e=q*8+j]
        const unsigned trb = lds_base + (unsigned)nat + tr_base;
        #pragma unroll
        for (int bb = 0; bb < 4; bb++) {        // dm = bb*4 .. +3
            const unsigned ab = trb + (unsigned)(bb * 512);
            f16x4 a0 = tr_rd0(ab);        f16x4 a1 = tr_rd1(ab);
            f16x4 a2 = tr_rd0(ab + 128);  f16x4 a3 = tr_rd1(ab + 128);
            f16x4 a4 = tr_rd0(ab + 256);  f16x4 a5 = tr_rd1(ab + 256);
            f16x4 a6 = tr_rd0(ab + 384);  f16x4 a7 = tr_rd1(ab + 384);
            asm volatile("s_waitcnt lgkmcnt(0)" ::: "memory");
            __builtin_amdgcn_sched_barrier(0);
            ctx[bb * 4 + 0] = MFMA16(SHUF8(a0, a1), pf, ctx[bb * 4 + 0]);
            ctx[bb * 4 + 1] = MFMA16(SHUF8(a2, a3), pf, ctx[bb * 4 + 1]);
            ctx[bb * 4 + 2] = MFMA16(SHUF8(a4, a5), pf, ctx[bb * 4 + 2]);
            ctx[bb * 4 + 3] = MFMA16(SHUF8(a6, a7), pf, ctx[bb * 4 + 3]);
        }
        __syncthreads();   // NAT dbuf protection; drains staging issued at iter top
    }

    // ---- epilogue: normalized partials; z=0 -> ctxp f16, z=1 -> out[0:256), z=2 -> out[256:512) ----
    const float inv = 1.0f / l_;
    const size_t row = (size_t)b * TD + t0 + tcol;
    if (z == 0) {
        f16* cb = ctxp + row * DIM;
        #pragma unroll
        for (int dm = 0; dm < 16; dm++) {
            f16x4 cv;
            #pragma unroll
            for (int r = 0; r < 4; r++) cv[r] = (f16)(ctx[dm][r] * inv);
            *(f16x4*)(cb + dm * 16 + q * 4) = cv;   // d = dm*16 + q*4 + r
        }
    } else {
        float* ob = out + row * 512 + (z == 2 ? 256 : 0);
        #pragma unroll
        for (int dm = 0; dm < 16; dm++) {
            float4 cv;
            cv.x = ctx[dm][0] * inv; cv.y = ctx[dm][1] * inv;
            cv.z = ctx[dm][2] * inv; cv.w = ctx[dm][3] * inv;
            *(float4*)(ob + dm * 16 + q * 4) = cv;
        }
    }
    if (q == 0) {
        f16x2 v; v[0] = (f16)m_; v[1] = (f16)l_;   // m_ exactly f16 (snapped)
        ml[(size_t)z * NBTD + row] = v;
    }
}

// ---------------- combine: merge 3 normalized partials + decoder passthrough ----------
__global__ __launch_bounds__(256) void combine_kernel(const float* __restrict__ dec32,
        const f16* __restrict__ ctxp, const f16x2* __restrict__ ml,
        float* __restrict__ out) {
    int idx  = blockIdx.x * 256 + threadIdx.x;
    int trow = idx >> 5;              // b*TD + t
    int dg   = (idx & 31) * 8;
    float m0[3], l0[3], M = -INFINITY;
    #pragma unroll
    for (int s = 0; s < 3; s++) {
        f16x2 v = ml[(size_t)s * NBTD + trow];
        m0[s] = (float)v[0];
        l0[s] = (float)v[1];
        M = fmaxf(M, m0[s]);
    }
    float L = 0.f, w[3];
    #pragma unroll
    for (int s = 0; s < 3; s++) {
        w[s] = __builtin_amdgcn_exp2f((m0[s] - M) * LOG2E) * l0[s];
        L += w[s];
    }
    float invL = 1.0f / L;
    float acc[8];
    {   // split 0: f16 partial in ctxp
        f16x8 v = *(const f16x8*)(ctxp + (size_t)trow * DIM + dg);
        float w0 = w[0] * invL;
        #pragma unroll
        for (int j = 0; j < 8; j++) acc[j] = w0 * (float)v[j];
    }
    {   // split 1: f32 partial parked in out's decoder area (read before overwrite)
        const float* o1 = out + (size_t)trow * 512 + dg;
        float4 p0 = *(const float4*)(o1);
        float4 p1 = *(const float4*)(o1 + 4);
        float w1 = w[1] * invL;
        acc[0] += w1 * p0.x; acc[1] += w1 * p0.y; acc[2] += w1 * p0.z; acc[3] += w1 * p0.w;
        acc[4] += w1 * p1.x; acc[5] += w1 * p1.y; acc[6] += w1 * p1.z; acc[7] += w1 * p1.w;
    }
    {   // split 2: f32 partial parked in out's context area
        const float* o2 = out + (size_t)trow * 512 + 256 + dg;
        float4 p0 = *(const float4*)(o2);
        float4 p1 = *(const float4*)(o2 + 4);
        float w2 = w[2] * invL;
        acc[0] += w2 * p0.x; acc[1] += w2 * p0.y; acc[2] += w2 * p0.z; acc[3] += w2 * p0.w;
        acc[4] += w2 * p1.x; acc[5] += w2 * p1.y; acc[6] += w2 * p1.z; acc[7] += w2 * p1.w;
    }
    float4 d0 = *(const float4*)(dec32 + (size_t)trow * DIM + dg);
    float4 d1 = *(const float4*)(dec32 + (size_t)trow * DIM + dg + 4);
    float* ob = out + (size_t)trow * 512;
    *(float4*)(ob + dg)     = d0;
    *(float4*)(ob + dg + 4) = d1;
    float4 c0, c1;
    c0.x=acc[0]; c0.y=acc[1]; c0.z=acc[2]; c0.w=acc[3];
    c1.x=acc[4]; c1.y=acc[5]; c1.z=acc[6]; c1.w=acc[7];
    *(float4*)(ob + 256 + dg)     = c0;
    *(float4*)(ob + 256 + dg + 4) = c1;
}

extern "C" void kernel_launch(void* const* d_in, const int* in_sizes, int n_in,
                              void* d_out, int out_size, void* d_ws, size_t ws_size,
                              hipStream_t stream) {
    (void)in_sizes; (void)n_in;
    const float* enc = (const float*)d_in[0];
    const float* dec = (const float*)d_in[1];
    float* out = (float*)d_out;

    const size_t MLB = (size_t)3 * NBTD * 4;          // 196,608 (f16x2 per split-row)
    const size_t HB  = (size_t)NB * TE * DIM * 2;     // 8,388,608 (ench)
    const size_t CSL = (size_t)NBTD * DIM * 2;        // 8,388,608 (1 f16 split)
    const size_t NEED = MLB + HB + CSL;               // 16,973,824 << proven 33.8 MB

    if (ws_size < NEED) {
        hipMemsetAsync(d_out, 0, (size_t)out_size * sizeof(float), stream);
        return;
    }
    f16x2* ml   = (f16x2*)d_ws;
    f16*   ench = (f16*)((char*)d_ws + MLB);
    f16*   ctxp = (f16*)((char*)d_ws + MLB + HB);

    prep_kernel<<<2048, 256, 0, stream>>>(enc, ench);
    attn_kernel<<<dim3(32, 8, 3), 256, 0, stream>>>(dec, ench, ctxp, ml, out);
    combine_kernel<<<2048, 256, 0, stream>>>(dec, ctxp, ml, out);
}